// Round 22
// baseline (439.000 us; speedup 1.0000x reference)
//
#include <hip/hip_runtime.h>

#define NN 100000
#define NE 1600000
#define NG 1024
#define D 64
#define DE 6
#define FAN 70
#define EPS 1e-5f

#define ENC_NEGINF 0x007FFFFFu
#define NINF (-__builtin_inff())

#define NBUK 782      // dst buckets of 128 nodes (782*128 = 100096)
#define TILE 4000     // edges per binA tile
#define NBLKA 400     // NE / TILE
#define BCAP 3072     // binB LDS esrc capacity
#define NBLKG 1563    // layer blocks: 64 rows each (1563*64 = 100032)

typedef __attribute__((ext_vector_type(8))) short short8;
typedef __attribute__((ext_vector_type(4))) float f32x4;

union U8 { unsigned u[4]; short8 s; };

__device__ __forceinline__ unsigned enc(float f) {
    unsigned u = __float_as_uint(f);
    return (u & 0x80000000u) ? ~u : (u | 0x80000000u);
}
__device__ __forceinline__ float dec(unsigned u) {
    return (u & 0x80000000u) ? __uint_as_float(u & 0x7FFFFFFFu) : __uint_as_float(~u);
}
__device__ __forceinline__ unsigned bfr(float f) {   // fp32 -> bf16 bits, RNE
    unsigned u = __float_as_uint(f);
    return (u + 0x7FFFu + ((u >> 16) & 1)) >> 16;
}
__device__ __forceinline__ float blo(unsigned w) { return __uint_as_float(w << 16); }
__device__ __forceinline__ float bhi(unsigned w) { return __uint_as_float(w & 0xFFFF0000u); }
__device__ __forceinline__ void bsplit(float a, unsigned& hi, unsigned& lo) {
    hi = bfr(a);
    lo = bfr(a - blo(hi));
}

// fp32 [NN][64] -> bf16-packed [NN][32] u32
__global__ void k_cast(const float4* __restrict__ in, uint2* __restrict__ out, int n4) {
    int i = blockIdx.x * 256 + threadIdx.x;
    if (i < n4) {
        float4 v = in[i];
        out[i] = make_uint2(bfr(v.x) | (bfr(v.y) << 16), bfr(v.z) | (bfr(v.w) << 16));
    }
}

// ---- pass A1: per-(tile,bucket) histogram ----
__launch_bounds__(256)
__global__ void k_binA1(const int* __restrict__ dst, int* __restrict__ cntA) {
    __shared__ int cnt[NBUK];
    int tid = threadIdx.x, blk = blockIdx.x;
    for (int i = tid; i < NBUK; i += 256) cnt[i] = 0;
    __syncthreads();
    int e0 = blk * TILE, e1 = min(e0 + TILE, NE);
    for (int e = e0 + tid; e < e1; e += 256) atomicAdd(&cnt[dst[e] >> 7], 1);
    __syncthreads();
    for (int i = tid; i < NBUK; i += 256) cntA[blk * NBUK + i] = cnt[i];
}

// ---- per-bucket exclusive scan over tiles ----
__global__ void k_scanA(const int* __restrict__ cntA, int* __restrict__ cofs,
                        int* __restrict__ buktot) {
    __shared__ int s[256];
    int b = blockIdx.x, t = threadIdx.x;
    int v0 = 0, v1 = 0;
    if (t < NBLKA / 2) {
        v0 = cntA[(2 * t) * NBUK + b];
        v1 = cntA[(2 * t + 1) * NBUK + b];
    }
    int sum = v0 + v1;
    s[t] = sum;
    __syncthreads();
    for (int off = 1; off < 256; off <<= 1) {
        int y = (t >= off) ? s[t - off] : 0;
        __syncthreads();
        s[t] += y;
        __syncthreads();
    }
    int excl = s[t] - sum;
    if (t < NBLKA / 2) {
        cofs[(2 * t) * NBUK + b] = excl;
        cofs[(2 * t + 1) * NBUK + b] = excl + v0;
    }
    if (t == 255) buktot[b] = s[255];
}

// ---- exclusive scan of 782 bucket totals ----
__global__ void k_bukscan(const int* __restrict__ buktot, int* __restrict__ bukbase) {
    __shared__ int s[1024];
    int t = threadIdx.x;
    int c = (t < NBUK) ? buktot[t] : 0;
    s[t] = c;
    __syncthreads();
    for (int off = 1; off < 1024; off <<= 1) {
        int y = (t >= off) ? s[t - off] : 0;
        __syncthreads();
        s[t] += y;
        __syncthreads();
    }
    if (t < NBUK) bukbase[t] = s[t] - c;
}

// ---- pass A2: coalesced dst read, exact-position 4B writes (eid<<7 | loc) ----
__launch_bounds__(256)
__global__ void k_binA2(const int* __restrict__ dst, const int* __restrict__ bukbase,
                        const int* __restrict__ cofs, unsigned* __restrict__ w0) {
    __shared__ int cursor[NBUK];
    int tid = threadIdx.x, blk = blockIdx.x;
    for (int i = tid; i < NBUK; i += 256) cursor[i] = bukbase[i] + cofs[blk * NBUK + i];
    __syncthreads();
    int e0 = blk * TILE, e1 = min(e0 + TILE, NE);
    for (int e = e0 + tid; e < e1; e += 256) {
        int d = dst[e];
        int b = d >> 7;
        int pos = atomicAdd(&cursor[b], 1);
        w0[pos] = ((unsigned)e << 7) | (unsigned)(d & 127);
    }
}

// ---- pass B: stream w0; random-gather src/ea; rowptr + esrc + eagg (LDS) ----
__launch_bounds__(512)
__global__ void k_binB(const unsigned* __restrict__ w0, const int* __restrict__ src,
                       const float* __restrict__ ea,
                       const int* __restrict__ bukbase, const int* __restrict__ buktot,
                       int* __restrict__ rowptr, int* __restrict__ esrc,
                       unsigned* __restrict__ eaggk) {
    __shared__ int cnt[256];
    __shared__ int base[256];
    __shared__ unsigned el[BCAP];            // 12 KB
    __shared__ unsigned emax[128 * DE];      // 3 KB
    int b = blockIdx.x, tid = threadIdx.x;
    int nb = b << 7;
    int nend = min(nb + 128, NN);
    int rb = bukbase[b];
    int tot = buktot[b];
    if (tid < 256) cnt[tid] = 0;
    for (int i = tid; i < 128 * DE; i += 512) emax[i] = ENC_NEGINF;
    __syncthreads();
    for (int i = tid; i < tot; i += 512) atomicAdd(&cnt[w0[rb + i] & 127], 1);
    __syncthreads();
    if (tid < 256) base[tid] = cnt[tid];
    __syncthreads();
    for (int off = 1; off < 256; off <<= 1) {
        int y = 0;
        if (tid < 256 && tid >= off) y = base[tid - off];
        __syncthreads();
        if (tid < 256) base[tid] += y;
        __syncthreads();
    }
    if (tid < 128) {
        int excl = base[tid] - cnt[tid];
        if (nb + tid < NN) rowptr[nb + tid] = rb + excl;
    }
    if (b == NBUK - 1 && tid == 0) rowptr[NN] = NE;
    __syncthreads();
    if (tid < 128) cnt[tid] = base[tid] - cnt[tid];   // cursor = exclusive
    __syncthreads();
    if (tot <= BCAP) {
        for (int i = tid; i < tot; i += 512) {
            unsigned ww = w0[rb + i];
            int loc = ww & 127;
            int eid = ww >> 7;
            int pos = atomicAdd(&cnt[loc], 1);
            el[pos] = (unsigned)src[eid];
            const float* pe = &ea[(size_t)eid * DE];
            #pragma unroll
            for (int t = 0; t < DE; ++t) atomicMax(&emax[loc * DE + t], enc(pe[t]));
        }
        __syncthreads();
        for (int i = tid; i < tot; i += 512) esrc[rb + i] = (int)el[i];
    } else {  // freak-overflow fallback: 4 loc-quarters (32 locs each)
        for (int h = 0; h < 4; ++h) {
            int lo = h * 32;
            int beg = (lo == 0) ? 0 : base[lo - 1];
            int sz = base[lo + 31] - beg;
            for (int i = tid; i < tot; i += 512) {
                unsigned ww = w0[rb + i];
                int loc = ww & 127;
                if ((loc >> 5) == h) {
                    int eid = ww >> 7;
                    int pos = atomicAdd(&cnt[loc], 1);
                    el[pos - beg] = (unsigned)src[eid];
                    const float* pe = &ea[(size_t)eid * DE];
                    #pragma unroll
                    for (int t = 0; t < DE; ++t) atomicMax(&emax[loc * DE + t], enc(pe[t]));
                }
            }
            __syncthreads();
            for (int i = tid; i < sz; i += 512) esrc[rb + beg + i] = (int)el[i];
            __syncthreads();
        }
    }
    __syncthreads();
    for (int i = tid; i < (nend - nb) * DE; i += 512) eaggk[nb * DE + i] = emax[i];
}

// ---- W split to bf16 hi/lo fragment-linear layout: Wf[ks][cb][lane][4 u32] ----
__global__ void k_wsplit(const float* __restrict__ W, unsigned* __restrict__ Wfhi,
                         unsigned* __restrict__ Wflo) {
    int t = blockIdx.x * 256 + threadIdx.x;     // 768 slots
    if (t >= 768) return;
    int l = t & 63, cb = (t >> 6) & 3, ks = t >> 8;
    int col = cb * 16 + (l & 15);
    int kbase = ks * 32 + (l >> 4) * 8;
    unsigned hi[8], lo[8];
    #pragma unroll
    for (int i = 0; i < 8; ++i) {
        int k = kbase + i;
        float wv = (k < FAN) ? W[k * 64 + col] : 0.f;
        bsplit(wv, hi[i], lo[i]);
    }
    *(uint4*)&Wfhi[t * 4] = make_uint4(hi[0] | (hi[1] << 16), hi[2] | (hi[3] << 16),
                                       hi[4] | (hi[5] << 16), hi[6] | (hi[7] << 16));
    *(uint4*)&Wflo[t * 4] = make_uint4(lo[0] | (lo[1] << 16), lo[2] | (lo[3] << 16),
                                       lo[4] | (lo[5] << 16), lo[6] | (lo[7] << 16));
}

// 8-deep reduce step: reads 8 rows of Xb for one node, folds into m/p trees
#define GATHER8(J, M0, P0, M1, P1)                                                        \
    {                                                                                     \
        unsigned g0 = Xb[(size_t)esrc[(J) + 0] * 32 + lt], g1 = Xb[(size_t)esrc[(J) + 1] * 32 + lt]; \
        unsigned g2 = Xb[(size_t)esrc[(J) + 2] * 32 + lt], g3 = Xb[(size_t)esrc[(J) + 3] * 32 + lt]; \
        unsigned g4 = Xb[(size_t)esrc[(J) + 4] * 32 + lt], g5 = Xb[(size_t)esrc[(J) + 5] * 32 + lt]; \
        unsigned g6 = Xb[(size_t)esrc[(J) + 6] * 32 + lt], g7 = Xb[(size_t)esrc[(J) + 7] * 32 + lt]; \
        M0 = fmaxf(M0, fmaxf(fmaxf(blo(g0), blo(g1)), fmaxf(blo(g2), blo(g3))));          \
        P0 = fmaxf(P0, fmaxf(fmaxf(blo(g4), blo(g5)), fmaxf(blo(g6), blo(g7))));          \
        M1 = fmaxf(M1, fmaxf(fmaxf(bhi(g0), bhi(g1)), fmaxf(bhi(g2), bhi(g3))));          \
        P1 = fmaxf(P1, fmaxf(fmaxf(bhi(g4), bhi(g5)), fmaxf(bhi(g6), bhi(g7))));          \
    }

// tail for one node: <8 edges left
#define GTAIL(J, RE, M0, P0, M1, P1)                                                      \
    for (; (J) + 2 <= (RE); (J) += 2) {                                                   \
        unsigned g0 = Xb[(size_t)esrc[(J)] * 32 + lt], g1 = Xb[(size_t)esrc[(J) + 1] * 32 + lt]; \
        M0 = fmaxf(M0, blo(g0)); P0 = fmaxf(P0, blo(g1));                                 \
        M1 = fmaxf(M1, bhi(g0)); P1 = fmaxf(P1, bhi(g1));                                 \
    }                                                                                     \
    if ((J) < (RE)) {                                                                     \
        unsigned g = Xb[(size_t)esrc[(J)] * 32 + lt];                                     \
        M0 = fmaxf(M0, blo(g)); M1 = fmaxf(M1, bhi(g));                                   \
    }

// finalize one node: fold p into m, apply norm/relu, emit
#define GFIN(HAS, M0, P0, M1, P1, A0, A1)                                                 \
    if (HAS) {                                                                            \
        M0 = fmaxf(M0, P0); M1 = fmaxf(M1, P1);                                           \
        if (apply) {                                                                      \
            A0 = fmaxf(fmaf(M0, s0, h0), 0.f);                                            \
            A1 = fmaxf(fmaf(M1, s1, h1), 0.f);                                            \
        } else { A0 = M0; A1 = M1; }                                                      \
    }

// ---------------- FUSED layer (512 thr, 64 nodes): gather -> LDS -> MFMA -> epilogue ----
// Gather: 16 half-waves x 4 nodes, 4-way interleaved (up to 32 in-flight loads/lane).
__launch_bounds__(512)
__global__ void k_layer(const unsigned* __restrict__ Xb, const int* __restrict__ rowptr,
                        const int* __restrict__ esrc, const unsigned* __restrict__ eaggk,
                        const float* __restrict__ ss, int apply,
                        const unsigned* __restrict__ Wfhi, const unsigned* __restrict__ Wflo,
                        const float* __restrict__ b,
                        unsigned* __restrict__ Hb, float* __restrict__ pstats) {
    __shared__ float Ag[64][76];   // 19.4 KB; Hl[64][68] aliases after fragment reads
    __shared__ float ls[128];
    int tid = threadIdx.x;
    int n0 = blockIdx.x * 64;

    // ---- phase 1: gather-max + prev-layer norm/relu, 4-node interleave ----
    int hw = tid >> 5, lt = tid & 31;
    float s0 = 1.f, h0 = 0.f, s1 = 1.f, h1 = 0.f;
    if (apply) {
        s0 = ss[2 * lt];     h0 = ss[D + 2 * lt];
        s1 = ss[2 * lt + 1]; h1 = ss[D + 2 * lt + 1];
    }
    {
        int r0 = hw * 4;
        int nA = n0 + r0, nB = nA + 1, nC = nA + 2, nD = nA + 3;
        int jA = 0, reA = 0, jB = 0, reB = 0, jC = 0, reC = 0, jD = 0, reD = 0;
        if (nA < NN) { jA = rowptr[nA]; reA = rowptr[nA + 1]; }
        if (nB < NN) { jB = rowptr[nB]; reB = rowptr[nB + 1]; }
        if (nC < NN) { jC = rowptr[nC]; reC = rowptr[nC + 1]; }
        if (nD < NN) { jD = rowptr[nD]; reD = rowptr[nD + 1]; }
        bool hasA = reA > jA, hasB = reB > jB, hasC = reC > jC, hasD = reD > jD;
        float mA0 = NINF, pA0 = NINF, mA1 = NINF, pA1 = NINF;
        float mB0 = NINF, pB0 = NINF, mB1 = NINF, pB1 = NINF;
        float mC0 = NINF, pC0 = NINF, mC1 = NINF, pC1 = NINF;
        float mD0 = NINF, pD0 = NINF, mD1 = NINF, pD1 = NINF;
        // 4-way interleaved main loop: 32 independent loads in flight
        while (jA + 8 <= reA && jB + 8 <= reB && jC + 8 <= reC && jD + 8 <= reD) {
            GATHER8(jA, mA0, pA0, mA1, pA1);
            GATHER8(jB, mB0, pB0, mB1, pB1);
            GATHER8(jC, mC0, pC0, mC1, pC1);
            GATHER8(jD, mD0, pD0, mD1, pD1);
            jA += 8; jB += 8; jC += 8; jD += 8;
        }
        // pairwise (A,B) and (C,D)
        while (jA + 8 <= reA && jB + 8 <= reB) {
            GATHER8(jA, mA0, pA0, mA1, pA1);
            GATHER8(jB, mB0, pB0, mB1, pB1);
            jA += 8; jB += 8;
        }
        while (jC + 8 <= reC && jD + 8 <= reD) {
            GATHER8(jC, mC0, pC0, mC1, pC1);
            GATHER8(jD, mD0, pD0, mD1, pD1);
            jC += 8; jD += 8;
        }
        // singles + tails
        for (; jA + 8 <= reA; jA += 8) GATHER8(jA, mA0, pA0, mA1, pA1);
        GTAIL(jA, reA, mA0, pA0, mA1, pA1);
        for (; jB + 8 <= reB; jB += 8) GATHER8(jB, mB0, pB0, mB1, pB1);
        GTAIL(jB, reB, mB0, pB0, mB1, pB1);
        for (; jC + 8 <= reC; jC += 8) GATHER8(jC, mC0, pC0, mC1, pC1);
        GTAIL(jC, reC, mC0, pC0, mC1, pC1);
        for (; jD + 8 <= reD; jD += 8) GATHER8(jD, mD0, pD0, mD1, pD1);
        GTAIL(jD, reD, mD0, pD0, mD1, pD1);
        float aA0 = 0.f, aA1 = 0.f, aB0 = 0.f, aB1 = 0.f;
        float aC0 = 0.f, aC1 = 0.f, aD0 = 0.f, aD1 = 0.f;
        GFIN(hasA, mA0, pA0, mA1, pA1, aA0, aA1);
        GFIN(hasB, mB0, pB0, mB1, pB1, aB0, aB1);
        GFIN(hasC, mC0, pC0, mC1, pC1, aC0, aC1);
        GFIN(hasD, mD0, pD0, mD1, pD1, aD0, aD1);
        *(float2*)&Ag[r0 + 0][2 * lt] = make_float2(aA0, aA1);
        *(float2*)&Ag[r0 + 1][2 * lt] = make_float2(aB0, aB1);
        *(float2*)&Ag[r0 + 2][2 * lt] = make_float2(aC0, aC1);
        *(float2*)&Ag[r0 + 3][2 * lt] = make_float2(aD0, aD1);
    }
    // eagg cols 64..69 (+ zero 70,71)
    for (int i = tid; i < 64 * 8; i += 512) {
        int r = i >> 3, c = i & 7;
        int n = n0 + r;
        float v = 0.f;
        if (c < DE && n < NN) {
            unsigned u = eaggk[n * DE + c];
            v = (u == ENC_NEGINF) ? 0.f : dec(u);
        }
        Ag[r][64 + c] = v;
    }
    if (tid < 128) ls[tid] = 0.f;
    __syncthreads();

    // ---- phase 2: fragments (register bsplit) + MFMA; wave w: rows (w&3)*16, cols (w>>2)*32 ----
    int w = tid >> 6, lane = tid & 63;
    int arow = (w & 3) * 16 + (lane & 15);
    int koff = (lane >> 4) * 8;
    int cb0 = (w >> 2) * 2;
    f32x4 acc[2];
    acc[0] = (f32x4){0.f, 0.f, 0.f, 0.f};
    acc[1] = (f32x4){0.f, 0.f, 0.f, 0.f};
    #pragma unroll
    for (int ks = 0; ks < 3; ++ks) {
        float av[8];
        if (ks < 2 || koff == 0) {
            *(float4*)&av[0] = *(const float4*)&Ag[arow][ks * 32 + koff];
            *(float4*)&av[4] = *(const float4*)&Ag[arow][ks * 32 + koff + 4];
        } else {
            #pragma unroll
            for (int i = 0; i < 8; ++i) av[i] = 0.f;
        }
        U8 ah, al;
        #pragma unroll
        for (int m = 0; m < 4; ++m) {
            unsigned h0b, l0b, h1b, l1b;
            bsplit(av[2 * m], h0b, l0b);
            bsplit(av[2 * m + 1], h1b, l1b);
            ah.u[m] = h0b | (h1b << 16);
            al.u[m] = l0b | (l1b << 16);
        }
        #pragma unroll
        for (int c = 0; c < 2; ++c) {
            int cb = cb0 + c;
            short8 wh = *(const short8*)&Wfhi[((ks * 4 + cb) * 64 + lane) * 4];
            short8 wl = *(const short8*)&Wflo[((ks * 4 + cb) * 64 + lane) * 4];
            acc[c] = __builtin_amdgcn_mfma_f32_16x16x32_bf16(ah.s, wh, acc[c], 0, 0, 0);
            acc[c] = __builtin_amdgcn_mfma_f32_16x16x32_bf16(al.s, wh, acc[c], 0, 0, 0);
            acc[c] = __builtin_amdgcn_mfma_f32_16x16x32_bf16(ah.s, wl, acc[c], 0, 0, 0);
        }
    }
    __syncthreads();   // all waves' Ag reads done; safe to overwrite with Hl

    // D -> LDS (C/D layout: col=lane&15, row=(lane>>4)*4+reg), stride 68
    float* Hl = &Ag[0][0];
    {
        int rbase = (w & 3) * 16 + ((lane >> 4) << 2);
        int cl = lane & 15;
        #pragma unroll
        for (int c = 0; c < 2; ++c)
            #pragma unroll
            for (int reg = 0; reg < 4; ++reg)
                Hl[(rbase + reg) * 68 + (cb0 + c) * 16 + cl] = acc[c][reg];
    }
    __syncthreads();

    // ---- epilogue: bias + stats + bf16 pack (coalesced); 512 thr, 2 rows each ----
    int tr = tid >> 4, tc = tid & 15, c0 = tc * 4;
    float4 bb = *(const float4*)&b[c0];
    float cs[4] = {0.f, 0.f, 0.f, 0.f};
    float cq[4] = {0.f, 0.f, 0.f, 0.f};
    #pragma unroll
    for (int i = 0; i < 2; i++) {
        int r = tr + 32 * i;
        int n = n0 + r;
        if (n < NN) {
            float4 hv = *(const float4*)&Hl[r * 68 + c0];
            float ox = hv.x + bb.x, oy = hv.y + bb.y, oz = hv.z + bb.z, ow = hv.w + bb.w;
            uint2 pk = make_uint2(bfr(ox) | (bfr(oy) << 16), bfr(oz) | (bfr(ow) << 16));
            *(uint2*)&Hb[(size_t)n * 32 + 2 * tc] = pk;
            cs[0] += ox; cs[1] += oy; cs[2] += oz; cs[3] += ow;
            cq[0] += ox * ox; cq[1] += oy * oy; cq[2] += oz * oz; cq[3] += ow * ow;
        }
    }
    #pragma unroll
    for (int jj = 0; jj < 4; jj++) {
        atomicAdd(&ls[c0 + jj], cs[jj]);
        atomicAdd(&ls[64 + c0 + jj], cq[jj]);
    }
    __syncthreads();
    if (tid < 128) pstats[(size_t)blockIdx.x * 128 + tid] = ls[tid];
}

// ---- stats reduce stage A: block j column-sums pstats[:, j] -> tot[j] ----
__global__ void k_redA(const float* __restrict__ pstats, float* __restrict__ tot) {
    __shared__ float red[256];
    int j = blockIdx.x, tid = threadIdx.x;   // 128 blocks x 256 threads
    float s = 0.f;
    for (int blk = tid; blk < NBLKG; blk += 256) s += pstats[(size_t)blk * 128 + j];
    red[tid] = s;
    __syncthreads();
    for (int off = 128; off > 0; off >>= 1) {
        if (tid < off) red[tid] += red[tid + off];
        __syncthreads();
    }
    if (tid == 0) tot[j] = red[0];
}

// ---- stats reduce stage B: finalize scale/shift ----
__global__ void k_redB(const float* __restrict__ tot, const float* __restrict__ g,
                       const float* __restrict__ beta, float* __restrict__ ss) {
    int j = threadIdx.x;  // 64 threads
    float mean = tot[j] * (1.0f / NN);
    float var = tot[64 + j] * (1.0f / NN) - mean * mean;
    float sc = rsqrtf(var + EPS) * g[j];
    ss[j] = sc;
    ss[64 + j] = beta[j] - mean * sc;
}

// graph offsets from sorted batch
__global__ void k_gptr(const int* __restrict__ batch, int* __restrict__ gptr) {
    int i = blockIdx.x * 256 + threadIdx.x;
    if (i >= NN) return;
    int b = batch[i];
    int prev = (i == 0) ? -1 : batch[i - 1];
    for (int g = prev + 1; g <= b; ++g) gptr[g] = i;
    if (i == NN - 1) {
        for (int g = b + 1; g <= NG; ++g) gptr[g] = NN;
    }
}

// pool(gather) + norm/relu + dot: half-wave per graph
__global__ void k_gfinal(const unsigned* __restrict__ Hb, const int* __restrict__ gptr,
                         const float* __restrict__ ss, const float* __restrict__ lw,
                         const float* __restrict__ lb, float* __restrict__ out) {
    int g = blockIdx.x * 8 + (threadIdx.x >> 5);
    int lt = threadIdx.x & 31;
    if (g >= NG) return;
    int rs = gptr[g], re = gptr[g + 1];
    float m0 = NINF, m1 = NINF, p0 = NINF, p1 = NINF;
    int n = rs;
    for (; n + 4 <= re; n += 4) {
        unsigned v0 = Hb[(size_t)(n + 0) * 32 + lt];
        unsigned v1 = Hb[(size_t)(n + 1) * 32 + lt];
        unsigned v2 = Hb[(size_t)(n + 2) * 32 + lt];
        unsigned v3 = Hb[(size_t)(n + 3) * 32 + lt];
        m0 = fmaxf(m0, fmaxf(blo(v0), blo(v1))); m1 = fmaxf(m1, fmaxf(bhi(v0), bhi(v1)));
        p0 = fmaxf(p0, fmaxf(blo(v2), blo(v3))); p1 = fmaxf(p1, fmaxf(bhi(v2), bhi(v3)));
    }
    for (; n < re; ++n) {
        unsigned v = Hb[(size_t)n * 32 + lt];
        m0 = fmaxf(m0, blo(v)); m1 = fmaxf(m1, bhi(v));
    }
    m0 = fmaxf(m0, p0);
    m1 = fmaxf(m1, p1);
    float a0 = (m0 == NINF) ? 0.f : fmaxf(fmaf(m0, ss[2 * lt], ss[D + 2 * lt]), 0.f);
    float a1 = (m1 == NINF) ? 0.f : fmaxf(fmaf(m1, ss[2 * lt + 1], ss[D + 2 * lt + 1]), 0.f);
    float p = fmaf(a0, lw[2 * lt], a1 * lw[2 * lt + 1]);
    #pragma unroll
    for (int off = 1; off < 32; off <<= 1) p += __shfl_xor(p, off);
    if (lt == 0) out[g] = p + lb[0];
}

extern "C" void kernel_launch(void* const* d_in, const int* in_sizes, int n_in,
                              void* d_out, int out_size, void* d_ws, size_t ws_size,
                              hipStream_t stream) {
    const float* x     = (const float*)d_in[0];
    const int*   ei    = (const int*)d_in[1];
    const float* ea    = (const float*)d_in[2];
    const int*   batch = (const int*)d_in[3];
    const float* Wp[3] = {(const float*)d_in[4],  (const float*)d_in[8],  (const float*)d_in[12]};
    const float* bp[3] = {(const float*)d_in[5],  (const float*)d_in[9],  (const float*)d_in[13]};
    const float* gp[3] = {(const float*)d_in[6],  (const float*)d_in[10], (const float*)d_in[14]};
    const float* tp[3] = {(const float*)d_in[7],  (const float*)d_in[11], (const float*)d_in[15]};
    const float* lw    = (const float*)d_in[16];
    const float* lb    = (const float*)d_in[17];
    float* out = (float*)d_out;

    const int* src = ei;
    const int* dst = ei + NE;

    // workspace layout (u32 word offsets); total ~43.8 MB
    unsigned* w = (unsigned*)d_ws;
    int*      rowptr  = (int*)w;                   // 100004
    int*      esrc    = (int*)(w + 100004);        // 1600000
    unsigned* eaggk   = w + 1700004;               // 600000
    float*    ss      = (float*)(w + 2300004);     // 128
    int*      gptr    = (int*)(w + 2300132);       // 1032
    int*      buktot  = (int*)(w + 2301164);       // 800
    int*      bukbase = (int*)(w + 2301964);       // 800
    unsigned* Wf      = w + 2302764;               // 6 x 3072 = 18432
    int*      cntA    = (int*)(w + 2321196);       // 312800
    int*      cofs    = (int*)(w + 2633996);       // 312800 -> end 2946796
    float*    pstats  = (float*)(w + 2321196);     // 1563*128 = 200064 (alias cntA; disjoint)
    unsigned* w0      = w + 2946796;               // 1600000 -> end 4546796
    unsigned* P       = w + 4546796;               // 3200000
    unsigned* Q       = w + 7746796;               // 3200000 -> end 10946796
    float*    tot     = (float*)(w + 10946796);    // 128 -> end 10946924 (43.8 MB)

    // --- W split (independent; once per layer) ---
    for (int l = 0; l < 3; ++l)
        k_wsplit<<<3, 256, 0, stream>>>(Wp[l], Wf + (2 * l) * 3072, Wf + (2 * l + 1) * 3072);

    // --- CSR + eagg: exact-placement binning, ea gathered once in binB ---
    k_binA1<<<NBLKA, 256, 0, stream>>>(dst, cntA);
    k_scanA<<<NBUK, 256, 0, stream>>>(cntA, cofs, buktot);
    k_bukscan<<<1, 1024, 0, stream>>>(buktot, bukbase);
    k_binA2<<<NBLKA, 256, 0, stream>>>(dst, bukbase, cofs, w0);
    k_binB<<<NBUK, 512, 0, stream>>>(w0, src, ea, bukbase, buktot, rowptr, esrc, eaggk);

    // --- bf16 cast + graph offsets ---
    k_cast<<<(NN * 16 + 255) / 256, 256, 0, stream>>>((const float4*)x, (uint2*)P, NN * 16);
    k_gptr<<<(NN + 255) / 256, 256, 0, stream>>>(batch, gptr);

    // --- 3 fused layers: ping-pong l0 P->Q, l1 Q->P, l2 P->Q ---
    const unsigned* lin[3]  = {P, Q, P};
    unsigned*       lout[3] = {Q, P, Q};
    for (int l = 0; l < 3; ++l) {
        k_layer<<<NBLKG, 512, 0, stream>>>(lin[l], rowptr, esrc, eaggk, ss, l > 0 ? 1 : 0,
                                           Wf + (2 * l) * 3072, Wf + (2 * l + 1) * 3072,
                                           bp[l], lout[l], pstats);
        k_redA<<<128, 256, 0, stream>>>(pstats, tot);
        k_redB<<<1, 64, 0, stream>>>(tot, gp[l], tp[l], ss);
    }

    // --- pooled gather + final norm/relu/dot ---
    k_gfinal<<<NG / 8, 256, 0, stream>>>(Q, gptr, ss, lw, lb, out);
}

// Round 23
// 381.816 us; speedup vs baseline: 1.1498x; 1.1498x over previous
//
#include <hip/hip_runtime.h>

#define NN 100000
#define NE 1600000
#define NG 1024
#define D 64
#define DE 6
#define FAN 70
#define EPS 1e-5f

#define ENC_NEGINF 0x007FFFFFu
#define NINF (-__builtin_inff())

#define NBUK 782      // dst buckets of 128 nodes (782*128 = 100096)
#define TILE 4000     // edges per binA tile
#define NBLKA 400     // NE / TILE
#define BCAP 3072     // binB LDS esrc capacity
#define NBLKG 1563    // layer blocks: 64 rows each (1563*64 = 100032)

typedef __attribute__((ext_vector_type(8))) short short8;
typedef __attribute__((ext_vector_type(4))) float f32x4;

union U8 { unsigned u[4]; short8 s; };

__device__ __forceinline__ unsigned enc(float f) {
    unsigned u = __float_as_uint(f);
    return (u & 0x80000000u) ? ~u : (u | 0x80000000u);
}
__device__ __forceinline__ float dec(unsigned u) {
    return (u & 0x80000000u) ? __uint_as_float(u & 0x7FFFFFFFu) : __uint_as_float(~u);
}
__device__ __forceinline__ unsigned bfr(float f) {   // fp32 -> bf16 bits, RNE
    unsigned u = __float_as_uint(f);
    return (u + 0x7FFFu + ((u >> 16) & 1)) >> 16;
}
__device__ __forceinline__ float blo(unsigned w) { return __uint_as_float(w << 16); }
__device__ __forceinline__ float bhi(unsigned w) { return __uint_as_float(w & 0xFFFF0000u); }
__device__ __forceinline__ void bsplit(float a, unsigned& hi, unsigned& lo) {
    hi = bfr(a);
    lo = bfr(a - blo(hi));
}

// fp32 [NN][64] -> bf16-packed [NN][32] u32
__global__ void k_cast(const float4* __restrict__ in, uint2* __restrict__ out, int n4) {
    int i = blockIdx.x * 256 + threadIdx.x;
    if (i < n4) {
        float4 v = in[i];
        out[i] = make_uint2(bfr(v.x) | (bfr(v.y) << 16), bfr(v.z) | (bfr(v.w) << 16));
    }
}

// ---- pass A1: per-(tile,bucket) histogram ----
__launch_bounds__(256)
__global__ void k_binA1(const int* __restrict__ dst, int* __restrict__ cntA) {
    __shared__ int cnt[NBUK];
    int tid = threadIdx.x, blk = blockIdx.x;
    for (int i = tid; i < NBUK; i += 256) cnt[i] = 0;
    __syncthreads();
    int e0 = blk * TILE, e1 = min(e0 + TILE, NE);
    for (int e = e0 + tid; e < e1; e += 256) atomicAdd(&cnt[dst[e] >> 7], 1);
    __syncthreads();
    for (int i = tid; i < NBUK; i += 256) cntA[blk * NBUK + i] = cnt[i];
}

// ---- per-bucket exclusive scan over tiles ----
__global__ void k_scanA(const int* __restrict__ cntA, int* __restrict__ cofs,
                        int* __restrict__ buktot) {
    __shared__ int s[256];
    int b = blockIdx.x, t = threadIdx.x;
    int v0 = 0, v1 = 0;
    if (t < NBLKA / 2) {
        v0 = cntA[(2 * t) * NBUK + b];
        v1 = cntA[(2 * t + 1) * NBUK + b];
    }
    int sum = v0 + v1;
    s[t] = sum;
    __syncthreads();
    for (int off = 1; off < 256; off <<= 1) {
        int y = (t >= off) ? s[t - off] : 0;
        __syncthreads();
        s[t] += y;
        __syncthreads();
    }
    int excl = s[t] - sum;
    if (t < NBLKA / 2) {
        cofs[(2 * t) * NBUK + b] = excl;
        cofs[(2 * t + 1) * NBUK + b] = excl + v0;
    }
    if (t == 255) buktot[b] = s[255];
}

// ---- exclusive scan of 782 bucket totals ----
__global__ void k_bukscan(const int* __restrict__ buktot, int* __restrict__ bukbase) {
    __shared__ int s[1024];
    int t = threadIdx.x;
    int c = (t < NBUK) ? buktot[t] : 0;
    s[t] = c;
    __syncthreads();
    for (int off = 1; off < 1024; off <<= 1) {
        int y = (t >= off) ? s[t - off] : 0;
        __syncthreads();
        s[t] += y;
        __syncthreads();
    }
    if (t < NBUK) bukbase[t] = s[t] - c;
}

// ---- pass A2: coalesced dst read, exact-position 4B writes (eid<<7 | loc) ----
__launch_bounds__(256)
__global__ void k_binA2(const int* __restrict__ dst, const int* __restrict__ bukbase,
                        const int* __restrict__ cofs, unsigned* __restrict__ w0) {
    __shared__ int cursor[NBUK];
    int tid = threadIdx.x, blk = blockIdx.x;
    for (int i = tid; i < NBUK; i += 256) cursor[i] = bukbase[i] + cofs[blk * NBUK + i];
    __syncthreads();
    int e0 = blk * TILE, e1 = min(e0 + TILE, NE);
    for (int e = e0 + tid; e < e1; e += 256) {
        int d = dst[e];
        int b = d >> 7;
        int pos = atomicAdd(&cursor[b], 1);
        w0[pos] = ((unsigned)e << 7) | (unsigned)(d & 127);
    }
}

// ---- pass B: stream w0; random-gather src/ea; rowptr + esrc + eagg (LDS) ----
__launch_bounds__(512)
__global__ void k_binB(const unsigned* __restrict__ w0, const int* __restrict__ src,
                       const float* __restrict__ ea,
                       const int* __restrict__ bukbase, const int* __restrict__ buktot,
                       int* __restrict__ rowptr, int* __restrict__ esrc,
                       unsigned* __restrict__ eaggk) {
    __shared__ int cnt[256];
    __shared__ int base[256];
    __shared__ unsigned el[BCAP];            // 12 KB
    __shared__ unsigned emax[128 * DE];      // 3 KB
    int b = blockIdx.x, tid = threadIdx.x;
    int nb = b << 7;
    int nend = min(nb + 128, NN);
    int rb = bukbase[b];
    int tot = buktot[b];
    if (tid < 256) cnt[tid] = 0;
    for (int i = tid; i < 128 * DE; i += 512) emax[i] = ENC_NEGINF;
    __syncthreads();
    for (int i = tid; i < tot; i += 512) atomicAdd(&cnt[w0[rb + i] & 127], 1);
    __syncthreads();
    if (tid < 256) base[tid] = cnt[tid];
    __syncthreads();
    for (int off = 1; off < 256; off <<= 1) {
        int y = 0;
        if (tid < 256 && tid >= off) y = base[tid - off];
        __syncthreads();
        if (tid < 256) base[tid] += y;
        __syncthreads();
    }
    if (tid < 128) {
        int excl = base[tid] - cnt[tid];
        if (nb + tid < NN) rowptr[nb + tid] = rb + excl;
    }
    if (b == NBUK - 1 && tid == 0) rowptr[NN] = NE;
    __syncthreads();
    if (tid < 128) cnt[tid] = base[tid] - cnt[tid];   // cursor = exclusive
    __syncthreads();
    if (tot <= BCAP) {
        for (int i = tid; i < tot; i += 512) {
            unsigned ww = w0[rb + i];
            int loc = ww & 127;
            int eid = ww >> 7;
            int pos = atomicAdd(&cnt[loc], 1);
            el[pos] = (unsigned)src[eid];
            const float* pe = &ea[(size_t)eid * DE];
            #pragma unroll
            for (int t = 0; t < DE; ++t) atomicMax(&emax[loc * DE + t], enc(pe[t]));
        }
        __syncthreads();
        for (int i = tid; i < tot; i += 512) esrc[rb + i] = (int)el[i];
    } else {  // freak-overflow fallback: 4 loc-quarters (32 locs each)
        for (int h = 0; h < 4; ++h) {
            int lo = h * 32;
            int beg = (lo == 0) ? 0 : base[lo - 1];
            int sz = base[lo + 31] - beg;
            for (int i = tid; i < tot; i += 512) {
                unsigned ww = w0[rb + i];
                int loc = ww & 127;
                if ((loc >> 5) == h) {
                    int eid = ww >> 7;
                    int pos = atomicAdd(&cnt[loc], 1);
                    el[pos - beg] = (unsigned)src[eid];
                    const float* pe = &ea[(size_t)eid * DE];
                    #pragma unroll
                    for (int t = 0; t < DE; ++t) atomicMax(&emax[loc * DE + t], enc(pe[t]));
                }
            }
            __syncthreads();
            for (int i = tid; i < sz; i += 512) esrc[rb + beg + i] = (int)el[i];
            __syncthreads();
        }
    }
    __syncthreads();
    for (int i = tid; i < (nend - nb) * DE; i += 512) eaggk[nb * DE + i] = emax[i];
}

// ---- W split to bf16 hi/lo fragment-linear layout: Wf[ks][cb][lane][4 u32] ----
__global__ void k_wsplit(const float* __restrict__ W, unsigned* __restrict__ Wfhi,
                         unsigned* __restrict__ Wflo) {
    int t = blockIdx.x * 256 + threadIdx.x;     // 768 slots
    if (t >= 768) return;
    int l = t & 63, cb = (t >> 6) & 3, ks = t >> 8;
    int col = cb * 16 + (l & 15);
    int kbase = ks * 32 + (l >> 4) * 8;
    unsigned hi[8], lo[8];
    #pragma unroll
    for (int i = 0; i < 8; ++i) {
        int k = kbase + i;
        float wv = (k < FAN) ? W[k * 64 + col] : 0.f;
        bsplit(wv, hi[i], lo[i]);
    }
    *(uint4*)&Wfhi[t * 4] = make_uint4(hi[0] | (hi[1] << 16), hi[2] | (hi[3] << 16),
                                       hi[4] | (hi[5] << 16), hi[6] | (hi[7] << 16));
    *(uint4*)&Wflo[t * 4] = make_uint4(lo[0] | (lo[1] << 16), lo[2] | (lo[3] << 16),
                                       lo[4] | (lo[5] << 16), lo[6] | (lo[7] << 16));
}

// 8-deep reduce step: reads 8 rows of Xb for one node, folds into m/p trees
#define GATHER8(J, M0, P0, M1, P1)                                                        \
    {                                                                                     \
        unsigned g0 = Xb[(size_t)esrc[(J) + 0] * 32 + lt], g1 = Xb[(size_t)esrc[(J) + 1] * 32 + lt]; \
        unsigned g2 = Xb[(size_t)esrc[(J) + 2] * 32 + lt], g3 = Xb[(size_t)esrc[(J) + 3] * 32 + lt]; \
        unsigned g4 = Xb[(size_t)esrc[(J) + 4] * 32 + lt], g5 = Xb[(size_t)esrc[(J) + 5] * 32 + lt]; \
        unsigned g6 = Xb[(size_t)esrc[(J) + 6] * 32 + lt], g7 = Xb[(size_t)esrc[(J) + 7] * 32 + lt]; \
        M0 = fmaxf(M0, fmaxf(fmaxf(blo(g0), blo(g1)), fmaxf(blo(g2), blo(g3))));          \
        P0 = fmaxf(P0, fmaxf(fmaxf(blo(g4), blo(g5)), fmaxf(blo(g6), blo(g7))));          \
        M1 = fmaxf(M1, fmaxf(fmaxf(bhi(g0), bhi(g1)), fmaxf(bhi(g2), bhi(g3))));          \
        P1 = fmaxf(P1, fmaxf(fmaxf(bhi(g4), bhi(g5)), fmaxf(bhi(g6), bhi(g7))));          \
    }

// ---------------- FUSED layer (512 thr, 64 nodes): gather -> LDS -> MFMA -> epilogue ----
// Gather: 16 half-waves x 4 nodes, processed as 2 interleaved pairs (2x in-flight loads).
__launch_bounds__(512)
__global__ void k_layer(const unsigned* __restrict__ Xb, const int* __restrict__ rowptr,
                        const int* __restrict__ esrc, const unsigned* __restrict__ eaggk,
                        const float* __restrict__ ss, int apply,
                        const unsigned* __restrict__ Wfhi, const unsigned* __restrict__ Wflo,
                        const float* __restrict__ b,
                        unsigned* __restrict__ Hb, float* __restrict__ pstats) {
    __shared__ float Ag[64][76];   // 19.4 KB; Hl[64][68] aliases after fragment reads
    __shared__ float ls[128];
    int tid = threadIdx.x;
    int n0 = blockIdx.x * 64;

    // ---- phase 1: gather-max + prev-layer norm/relu, pairs interleaved ----
    int hw = tid >> 5, lt = tid & 31;
    float s0 = 1.f, h0 = 0.f, s1 = 1.f, h1 = 0.f;
    if (apply) {
        s0 = ss[2 * lt];     h0 = ss[D + 2 * lt];
        s1 = ss[2 * lt + 1]; h1 = ss[D + 2 * lt + 1];
    }
    for (int qp = 0; qp < 2; ++qp) {
        int rA = hw * 4 + 2 * qp, rB = rA + 1;
        int nA = n0 + rA, nB = n0 + rB;
        int jA = 0, reA = 0, jB = 0, reB = 0;
        if (nA < NN) { jA = rowptr[nA]; reA = rowptr[nA + 1]; }
        if (nB < NN) { jB = rowptr[nB]; reB = rowptr[nB + 1]; }
        bool hasA = reA > jA, hasB = reB > jB;
        float mA0 = NINF, pA0 = NINF, mA1 = NINF, pA1 = NINF;
        float mB0 = NINF, pB0 = NINF, mB1 = NINF, pB1 = NINF;
        // interleaved main loop: 16 independent loads in flight
        while (jA + 8 <= reA && jB + 8 <= reB) {
            GATHER8(jA, mA0, pA0, mA1, pA1);
            GATHER8(jB, mB0, pB0, mB1, pB1);
            jA += 8; jB += 8;
        }
        // finish A
        for (; jA + 8 <= reA; jA += 8) GATHER8(jA, mA0, pA0, mA1, pA1);
        for (; jA + 2 <= reA; jA += 2) {
            unsigned g0 = Xb[(size_t)esrc[jA] * 32 + lt], g1 = Xb[(size_t)esrc[jA + 1] * 32 + lt];
            mA0 = fmaxf(mA0, blo(g0)); pA0 = fmaxf(pA0, blo(g1));
            mA1 = fmaxf(mA1, bhi(g0)); pA1 = fmaxf(pA1, bhi(g1));
        }
        if (jA < reA) {
            unsigned g = Xb[(size_t)esrc[jA] * 32 + lt];
            mA0 = fmaxf(mA0, blo(g)); mA1 = fmaxf(mA1, bhi(g));
        }
        // finish B
        for (; jB + 8 <= reB; jB += 8) GATHER8(jB, mB0, pB0, mB1, pB1);
        for (; jB + 2 <= reB; jB += 2) {
            unsigned g0 = Xb[(size_t)esrc[jB] * 32 + lt], g1 = Xb[(size_t)esrc[jB + 1] * 32 + lt];
            mB0 = fmaxf(mB0, blo(g0)); pB0 = fmaxf(pB0, blo(g1));
            mB1 = fmaxf(mB1, bhi(g0)); pB1 = fmaxf(pB1, bhi(g1));
        }
        if (jB < reB) {
            unsigned g = Xb[(size_t)esrc[jB] * 32 + lt];
            mB0 = fmaxf(mB0, blo(g)); mB1 = fmaxf(mB1, bhi(g));
        }
        float aA0 = 0.f, aA1 = 0.f, aB0 = 0.f, aB1 = 0.f;
        if (hasA) {
            mA0 = fmaxf(mA0, pA0); mA1 = fmaxf(mA1, pA1);
            if (apply) {
                aA0 = fmaxf(fmaf(mA0, s0, h0), 0.f);
                aA1 = fmaxf(fmaf(mA1, s1, h1), 0.f);
            } else { aA0 = mA0; aA1 = mA1; }
        }
        if (hasB) {
            mB0 = fmaxf(mB0, pB0); mB1 = fmaxf(mB1, pB1);
            if (apply) {
                aB0 = fmaxf(fmaf(mB0, s0, h0), 0.f);
                aB1 = fmaxf(fmaf(mB1, s1, h1), 0.f);
            } else { aB0 = mB0; aB1 = mB1; }
        }
        *(float2*)&Ag[rA][2 * lt] = make_float2(aA0, aA1);
        *(float2*)&Ag[rB][2 * lt] = make_float2(aB0, aB1);
    }
    // eagg cols 64..69 (+ zero 70,71)
    for (int i = tid; i < 64 * 8; i += 512) {
        int r = i >> 3, c = i & 7;
        int n = n0 + r;
        float v = 0.f;
        if (c < DE && n < NN) {
            unsigned u = eaggk[n * DE + c];
            v = (u == ENC_NEGINF) ? 0.f : dec(u);
        }
        Ag[r][64 + c] = v;
    }
    if (tid < 128) ls[tid] = 0.f;
    __syncthreads();

    // ---- phase 2: fragments (register bsplit) + MFMA; wave w: rows (w&3)*16, cols (w>>2)*32 ----
    int w = tid >> 6, lane = tid & 63;
    int arow = (w & 3) * 16 + (lane & 15);
    int koff = (lane >> 4) * 8;
    int cb0 = (w >> 2) * 2;
    f32x4 acc[2];
    acc[0] = (f32x4){0.f, 0.f, 0.f, 0.f};
    acc[1] = (f32x4){0.f, 0.f, 0.f, 0.f};
    #pragma unroll
    for (int ks = 0; ks < 3; ++ks) {
        float av[8];
        if (ks < 2 || koff == 0) {
            *(float4*)&av[0] = *(const float4*)&Ag[arow][ks * 32 + koff];
            *(float4*)&av[4] = *(const float4*)&Ag[arow][ks * 32 + koff + 4];
        } else {
            #pragma unroll
            for (int i = 0; i < 8; ++i) av[i] = 0.f;
        }
        U8 ah, al;
        #pragma unroll
        for (int m = 0; m < 4; ++m) {
            unsigned h0b, l0b, h1b, l1b;
            bsplit(av[2 * m], h0b, l0b);
            bsplit(av[2 * m + 1], h1b, l1b);
            ah.u[m] = h0b | (h1b << 16);
            al.u[m] = l0b | (l1b << 16);
        }
        #pragma unroll
        for (int c = 0; c < 2; ++c) {
            int cb = cb0 + c;
            short8 wh = *(const short8*)&Wfhi[((ks * 4 + cb) * 64 + lane) * 4];
            short8 wl = *(const short8*)&Wflo[((ks * 4 + cb) * 64 + lane) * 4];
            acc[c] = __builtin_amdgcn_mfma_f32_16x16x32_bf16(ah.s, wh, acc[c], 0, 0, 0);
            acc[c] = __builtin_amdgcn_mfma_f32_16x16x32_bf16(al.s, wh, acc[c], 0, 0, 0);
            acc[c] = __builtin_amdgcn_mfma_f32_16x16x32_bf16(ah.s, wl, acc[c], 0, 0, 0);
        }
    }
    __syncthreads();   // all waves' Ag reads done; safe to overwrite with Hl

    // D -> LDS (C/D layout: col=lane&15, row=(lane>>4)*4+reg), stride 68
    float* Hl = &Ag[0][0];
    {
        int rbase = (w & 3) * 16 + ((lane >> 4) << 2);
        int cl = lane & 15;
        #pragma unroll
        for (int c = 0; c < 2; ++c)
            #pragma unroll
            for (int reg = 0; reg < 4; ++reg)
                Hl[(rbase + reg) * 68 + (cb0 + c) * 16 + cl] = acc[c][reg];
    }
    __syncthreads();

    // ---- epilogue: bias + stats + bf16 pack (coalesced); 512 thr, 2 rows each ----
    int tr = tid >> 4, tc = tid & 15, c0 = tc * 4;
    float4 bb = *(const float4*)&b[c0];
    float cs[4] = {0.f, 0.f, 0.f, 0.f};
    float cq[4] = {0.f, 0.f, 0.f, 0.f};
    #pragma unroll
    for (int i = 0; i < 2; i++) {
        int r = tr + 32 * i;
        int n = n0 + r;
        if (n < NN) {
            float4 hv = *(const float4*)&Hl[r * 68 + c0];
            float ox = hv.x + bb.x, oy = hv.y + bb.y, oz = hv.z + bb.z, ow = hv.w + bb.w;
            uint2 pk = make_uint2(bfr(ox) | (bfr(oy) << 16), bfr(oz) | (bfr(ow) << 16));
            *(uint2*)&Hb[(size_t)n * 32 + 2 * tc] = pk;
            cs[0] += ox; cs[1] += oy; cs[2] += oz; cs[3] += ow;
            cq[0] += ox * ox; cq[1] += oy * oy; cq[2] += oz * oz; cq[3] += ow * ow;
        }
    }
    #pragma unroll
    for (int jj = 0; jj < 4; jj++) {
        atomicAdd(&ls[c0 + jj], cs[jj]);
        atomicAdd(&ls[64 + c0 + jj], cq[jj]);
    }
    __syncthreads();
    if (tid < 128) pstats[(size_t)blockIdx.x * 128 + tid] = ls[tid];
}

// ---- stats reduce stage A: block j column-sums pstats[:, j] -> tot[j] ----
__global__ void k_redA(const float* __restrict__ pstats, float* __restrict__ tot) {
    __shared__ float red[256];
    int j = blockIdx.x, tid = threadIdx.x;   // 128 blocks x 256 threads
    float s = 0.f;
    for (int blk = tid; blk < NBLKG; blk += 256) s += pstats[(size_t)blk * 128 + j];
    red[tid] = s;
    __syncthreads();
    for (int off = 128; off > 0; off >>= 1) {
        if (tid < off) red[tid] += red[tid + off];
        __syncthreads();
    }
    if (tid == 0) tot[j] = red[0];
}

// ---- stats reduce stage B: finalize scale/shift ----
__global__ void k_redB(const float* __restrict__ tot, const float* __restrict__ g,
                       const float* __restrict__ beta, float* __restrict__ ss) {
    int j = threadIdx.x;  // 64 threads
    float mean = tot[j] * (1.0f / NN);
    float var = tot[64 + j] * (1.0f / NN) - mean * mean;
    float sc = rsqrtf(var + EPS) * g[j];
    ss[j] = sc;
    ss[64 + j] = beta[j] - mean * sc;
}

// graph offsets from sorted batch
__global__ void k_gptr(const int* __restrict__ batch, int* __restrict__ gptr) {
    int i = blockIdx.x * 256 + threadIdx.x;
    if (i >= NN) return;
    int b = batch[i];
    int prev = (i == 0) ? -1 : batch[i - 1];
    for (int g = prev + 1; g <= b; ++g) gptr[g] = i;
    if (i == NN - 1) {
        for (int g = b + 1; g <= NG; ++g) gptr[g] = NN;
    }
}

// pool(gather) + norm/relu + dot: half-wave per graph
__global__ void k_gfinal(const unsigned* __restrict__ Hb, const int* __restrict__ gptr,
                         const float* __restrict__ ss, const float* __restrict__ lw,
                         const float* __restrict__ lb, float* __restrict__ out) {
    int g = blockIdx.x * 8 + (threadIdx.x >> 5);
    int lt = threadIdx.x & 31;
    if (g >= NG) return;
    int rs = gptr[g], re = gptr[g + 1];
    float m0 = NINF, m1 = NINF, p0 = NINF, p1 = NINF;
    int n = rs;
    for (; n + 4 <= re; n += 4) {
        unsigned v0 = Hb[(size_t)(n + 0) * 32 + lt];
        unsigned v1 = Hb[(size_t)(n + 1) * 32 + lt];
        unsigned v2 = Hb[(size_t)(n + 2) * 32 + lt];
        unsigned v3 = Hb[(size_t)(n + 3) * 32 + lt];
        m0 = fmaxf(m0, fmaxf(blo(v0), blo(v1))); m1 = fmaxf(m1, fmaxf(bhi(v0), bhi(v1)));
        p0 = fmaxf(p0, fmaxf(blo(v2), blo(v3))); p1 = fmaxf(p1, fmaxf(bhi(v2), bhi(v3)));
    }
    for (; n < re; ++n) {
        unsigned v = Hb[(size_t)n * 32 + lt];
        m0 = fmaxf(m0, blo(v)); m1 = fmaxf(m1, bhi(v));
    }
    m0 = fmaxf(m0, p0);
    m1 = fmaxf(m1, p1);
    float a0 = (m0 == NINF) ? 0.f : fmaxf(fmaf(m0, ss[2 * lt], ss[D + 2 * lt]), 0.f);
    float a1 = (m1 == NINF) ? 0.f : fmaxf(fmaf(m1, ss[2 * lt + 1], ss[D + 2 * lt + 1]), 0.f);
    float p = fmaf(a0, lw[2 * lt], a1 * lw[2 * lt + 1]);
    #pragma unroll
    for (int off = 1; off < 32; off <<= 1) p += __shfl_xor(p, off);
    if (lt == 0) out[g] = p + lb[0];
}

extern "C" void kernel_launch(void* const* d_in, const int* in_sizes, int n_in,
                              void* d_out, int out_size, void* d_ws, size_t ws_size,
                              hipStream_t stream) {
    const float* x     = (const float*)d_in[0];
    const int*   ei    = (const int*)d_in[1];
    const float* ea    = (const float*)d_in[2];
    const int*   batch = (const int*)d_in[3];
    const float* Wp[3] = {(const float*)d_in[4],  (const float*)d_in[8],  (const float*)d_in[12]};
    const float* bp[3] = {(const float*)d_in[5],  (const float*)d_in[9],  (const float*)d_in[13]};
    const float* gp[3] = {(const float*)d_in[6],  (const float*)d_in[10], (const float*)d_in[14]};
    const float* tp[3] = {(const float*)d_in[7],  (const float*)d_in[11], (const float*)d_in[15]};
    const float* lw    = (const float*)d_in[16];
    const float* lb    = (const float*)d_in[17];
    float* out = (float*)d_out;

    const int* src = ei;
    const int* dst = ei + NE;

    // workspace layout (u32 word offsets); total ~43.8 MB
    unsigned* w = (unsigned*)d_ws;
    int*      rowptr  = (int*)w;                   // 100004
    int*      esrc    = (int*)(w + 100004);        // 1600000
    unsigned* eaggk   = w + 1700004;               // 600000
    float*    ss      = (float*)(w + 2300004);     // 128
    int*      gptr    = (int*)(w + 2300132);       // 1032
    int*      buktot  = (int*)(w + 2301164);       // 800
    int*      bukbase = (int*)(w + 2301964);       // 800
    unsigned* Wf      = w + 2302764;               // 6 x 3072 = 18432
    int*      cntA    = (int*)(w + 2321196);       // 312800
    int*      cofs    = (int*)(w + 2633996);       // 312800 -> end 2946796
    float*    pstats  = (float*)(w + 2321196);     // 1563*128 = 200064 (alias cntA; disjoint)
    unsigned* w0      = w + 2946796;               // 1600000 -> end 4546796
    unsigned* P       = w + 4546796;               // 3200000
    unsigned* Q       = w + 7746796;               // 3200000 -> end 10946796
    float*    tot     = (float*)(w + 10946796);    // 128 -> end 10946924 (43.8 MB)

    // --- W split (independent; once per layer) ---
    for (int l = 0; l < 3; ++l)
        k_wsplit<<<3, 256, 0, stream>>>(Wp[l], Wf + (2 * l) * 3072, Wf + (2 * l + 1) * 3072);

    // --- CSR + eagg: exact-placement binning, ea gathered once in binB ---
    k_binA1<<<NBLKA, 256, 0, stream>>>(dst, cntA);
    k_scanA<<<NBUK, 256, 0, stream>>>(cntA, cofs, buktot);
    k_bukscan<<<1, 1024, 0, stream>>>(buktot, bukbase);
    k_binA2<<<NBLKA, 256, 0, stream>>>(dst, bukbase, cofs, w0);
    k_binB<<<NBUK, 512, 0, stream>>>(w0, src, ea, bukbase, buktot, rowptr, esrc, eaggk);

    // --- bf16 cast + graph offsets ---
    k_cast<<<(NN * 16 + 255) / 256, 256, 0, stream>>>((const float4*)x, (uint2*)P, NN * 16);
    k_gptr<<<(NN + 255) / 256, 256, 0, stream>>>(batch, gptr);

    // --- 3 fused layers: ping-pong l0 P->Q, l1 Q->P, l2 P->Q ---
    const unsigned* lin[3]  = {P, Q, P};
    unsigned*       lout[3] = {Q, P, Q};
    for (int l = 0; l < 3; ++l) {
        k_layer<<<NBLKG, 512, 0, stream>>>(lin[l], rowptr, esrc, eaggk, ss, l > 0 ? 1 : 0,
                                           Wf + (2 * l) * 3072, Wf + (2 * l + 1) * 3072,
                                           bp[l], lout[l], pstats);
        k_redA<<<128, 256, 0, stream>>>(pstats, tot);
        k_redB<<<1, 64, 0, stream>>>(tot, gp[l], tp[l], ss);
    }

    // --- pooled gather + final norm/relu/dot ---
    k_gfinal<<<NG / 8, 256, 0, stream>>>(Q, gptr, ss, lw, lb, out);
}